// Round 4
// baseline (812.002 us; speedup 1.0000x reference)
//
#include <hip/hip_runtime.h>

#define B_    512
#define V_    50000
#define VP    50048   // padded vocab (64*782)
#define KT    200     // topics
#define HH    300     // embedding dim
#define HIDN  800     // hidden
#define KP    224     // padded topic dim (7*32)
#define HP    320     // padded embedding dim (10*32)
#define NVB   782     // VP/64 v-blocks (consumer partials per doc)

typedef __attribute__((ext_vector_type(4))) float  f32x4;
typedef __attribute__((ext_vector_type(8))) short  s8v;
typedef __attribute__((ext_vector_type(8))) __bf16 bf16x8;
typedef unsigned int u32;

static __device__ __forceinline__ f32x4 mfma16(s8v a, s8v b, f32x4 c){
  return __builtin_amdgcn_mfma_f32_16x16x32_bf16(
      __builtin_bit_cast(bf16x8, a), __builtin_bit_cast(bf16x8, b), c, 0, 0, 0);
}
static __device__ __forceinline__ short f2bf(float f){
  unsigned u = __float_as_uint(f);
  u = (u + 0x7fffu + ((u >> 16) & 1u)) >> 16;
  return (short)u;
}
// async global->LDS, 16B per lane; LDS dest = wave-uniform base + lane*16
static __device__ __forceinline__ void load_lds16(const short* g, short* lds){
  __builtin_amdgcn_global_load_lds(
      (const __attribute__((address_space(1))) u32*)g,
      (__attribute__((address_space(3))) u32*)lds, 16, 0, 0);
}

// ---------------- zero init ----------------
__global__ void kzero(float* p, long n){
  long i = blockIdx.x * (long)blockDim.x + threadIdx.x;
  long st = (long)gridDim.x * blockDim.x;
  for(; i < n; i += st) p[i] = 0.f;
}

// ---------------- bows fp32 -> bf16 (rows padded to VP) + per-doc token counts ----------------
__global__ __launch_bounds__(256) void k_bows(const float* __restrict__ src,
                                              short* __restrict__ dst,
                                              float* __restrict__ ntok_acc){
  __shared__ float r4[4];
  int b = blockIdx.y;
  int c = blockIdx.x * 256 + threadIdx.x;          // chunk of 8 shorts
  int lane = threadIdx.x & 63, w = threadIdx.x >> 6;
  float s = 0.f;
  if(c < VP / 8){
    int v = c * 8;
    s8v o = {0,0,0,0,0,0,0,0};
    if(v + 8 <= V_){
      float4 a = *(const float4*)&src[(long)b * V_ + v];
      float4 d = *(const float4*)&src[(long)b * V_ + v + 4];
      o[0]=f2bf(a.x); o[1]=f2bf(a.y); o[2]=f2bf(a.z); o[3]=f2bf(a.w);
      o[4]=f2bf(d.x); o[5]=f2bf(d.y); o[6]=f2bf(d.z); o[7]=f2bf(d.w);
      s = a.x + a.y + a.z + a.w + d.x + d.y + d.z + d.w;
    }
    *(s8v*)&dst[(long)b * VP + v] = o;
  }
  #pragma unroll
  for(int k = 32; k >= 1; k >>= 1) s += __shfl_xor(s, k, 64);
  if(lane == 0) r4[w] = s;
  __syncthreads();
  if(threadIdx.x == 0) atomicAdd(&ntok_acc[b], r4[0] + r4[1] + r4[2] + r4[3]);
}

// ---------------- W1 (V x HIDN fp32) -> W1t (HIDN x VP bf16, transposed) ----------------
__global__ __launch_bounds__(256) void k_transW1(const float* __restrict__ W1,
                                                 short* __restrict__ W1t){
  __shared__ float tile[32][33];
  int v0 = blockIdx.x * 32, n0 = blockIdx.y * 32;
  int tid = threadIdx.x;
  int r = tid >> 3, c4 = (tid & 7) * 4;
  float4 val = {0.f,0.f,0.f,0.f};
  int v = v0 + r;
  if(v < V_) val = *(const float4*)&W1[(long)v * HIDN + n0 + c4];
  tile[r][c4+0] = val.x; tile[r][c4+1] = val.y; tile[r][c4+2] = val.z; tile[r][c4+3] = val.w;
  __syncthreads();
  short4 o;
  o.x = f2bf(tile[c4+0][r]); o.y = f2bf(tile[c4+1][r]);
  o.z = f2bf(tile[c4+2][r]); o.w = f2bf(tile[c4+3][r]);
  *(short4*)&W1t[(long)(n0 + r) * VP + v0 + c4] = o;
}

// ---------------- fp32 -> bf16 with row padding (blockDim = kpad) ----------------
__global__ void kconvpad(const float* __restrict__ src, short* __restrict__ dst,
                         int kin, int kpad){
  int r = blockIdx.x, c = threadIdx.x;
  float v = (c < kin) ? src[(long)r * kin + c] : 0.f;
  dst[(long)r * kpad + c] = f2bf(v);
}

// ---------------- GEMM1: hid_acc += bows @ W1 (split-K, atomic) ----------------
// Ring-3 LDS + counted vmcnt; K-MAJOR LDS layout: granule g = kg*16 + row so the
// fragment ds_read_b128 hits bank lm*4%32 (2-way = free) instead of the row-major
// 8-way conflict (rows at 64B stride all land on banks {0,16}).
// Staging keeps LDS dest linear; the per-lane GLOBAL address is permuted instead
// (lane -> row=lane&15, kg=lane>>4). Same cache-line set, same coalescing.
__global__ __launch_bounds__(256) void k_gemm1(const short* __restrict__ Ab,
                                               const short* __restrict__ Bb,
                                               float* __restrict__ Cacc){
  __shared__ short As[3][128 * 32];
  __shared__ short Bs[3][128 * 32];
  int tid = threadIdx.x, w = tid >> 6, lane = tid & 63, lm = lane & 15, q = lane >> 4;
  int f = blockIdx.x;                       // 896 = 8 XCDs * 112
  int lid = (f & 7) * 112 + (f >> 3);       // logical id, z-major
  int z = lid / 28, rem = lid % 28;         // 28 = 7 n-blocks * 4 m-blocks per k-slice
  int by = rem >> 2, bx = rem & 3;
  int m0 = bx * 128, n0 = by * 128;
  long kstart = (long)z * 1568;
  long kend = kstart + 1568; if(kend > VP) kend = VP;
  int nt = (int)((kend - kstart) >> 5);     // K-steps of 32
  int rsub = lane & 15;          // row within 16-row chunk (k-major)
  int kl = (lane >> 4) * 8;      // k-granule offset in shorts
  int rA0 = m0 + w * 16 + rsub;
  int rA1 = m0 + (w + 4) * 16 + rsub;
  int nB0 = n0 + w * 16 + rsub;       if(nB0 > HIDN - 1) nB0 = HIDN - 1;
  int nB1 = n0 + (w + 4) * 16 + rsub; if(nB1 > HIDN - 1) nB1 = HIDN - 1;
  f32x4 acc[2][8];
  #pragma unroll
  for(int i = 0; i < 2; i++)
    #pragma unroll
    for(int j = 0; j < 8; j++) acc[i][j] = (f32x4){0.f,0.f,0.f,0.f};

  auto STAGE = [&](int buf, int t){
    long kb = kstart + ((long)t << 5);
    load_lds16(&Ab[(long)rA0 * VP + kb + kl], &As[buf][w * 512]);
    load_lds16(&Ab[(long)rA1 * VP + kb + kl], &As[buf][(w + 4) * 512]);
    load_lds16(&Bb[(long)nB0 * VP + kb + kl], &Bs[buf][w * 512]);
    load_lds16(&Bb[(long)nB1 * VP + kb + kl], &Bs[buf][(w + 4) * 512]);
  };

  STAGE(0, 0);
  if(nt > 1) STAGE(1, 1);
  int cb = 0, sb = 2;
  for(int t = 0; t < nt; t++){
    if(t < nt - 1) asm volatile("s_waitcnt vmcnt(4)\n\ts_barrier" ::: "memory");
    else           asm volatile("s_waitcnt vmcnt(0)\n\ts_barrier" ::: "memory");
    if(t + 2 < nt) STAGE(sb, t + 2);
    s8v af[2], bfr[8];
    #pragma unroll
    for(int i = 0; i < 2; i++) af[i]  = *(const s8v*)&As[cb][(w * 2 + i) * 512 + q * 128 + lm * 8];
    #pragma unroll
    for(int j = 0; j < 8; j++) bfr[j] = *(const s8v*)&Bs[cb][j * 512 + q * 128 + lm * 8];
    #pragma unroll
    for(int i = 0; i < 2; i++)
      #pragma unroll
      for(int j = 0; j < 8; j++)
        acc[i][j] = mfma16(af[i], bfr[j], acc[i][j]);
    cb = (cb == 2) ? 0 : cb + 1;
    sb = (sb == 2) ? 0 : sb + 1;
  }
  #pragma unroll
  for(int i = 0; i < 2; i++)
    #pragma unroll
    for(int j = 0; j < 8; j++){
      int gm = m0 + w * 32 + i * 16 + q * 4;
      int gn = n0 + j * 16 + lm;
      if(gn < HIDN){
        #pragma unroll
        for(int r = 0; r < 4; r++) atomicAdd(&Cacc[(long)(gm + r) * HIDN + gn], acc[i][j][r]);
      }
    }
}

// ---------------- theta: relu(hid+b1) @ W2 + b2 -> softplus -> softmax / scaled ----------------
__global__ __launch_bounds__(256) void k_theta(const float* __restrict__ hid_acc,
                                               const float* __restrict__ b1,
                                               const float* __restrict__ W2,
                                               const float* __restrict__ b2,
                                               const float* __restrict__ sumexp,
                                               short* __restrict__ thetas_b,
                                               short* __restrict__ thetan_b,
                                               float* __restrict__ thetan_f){
  __shared__ float hrow[HIDN];
  __shared__ float thl[256];
  __shared__ float redm[4], reds[4];
  int b = blockIdx.x, tid = threadIdx.x;
  for(int h = tid; h < HIDN; h += 256){
    float x = hid_acc[(long)b * HIDN + h] + b1[h];
    hrow[h] = x > 0.f ? x : 0.f;
  }
  __syncthreads();
  float th = 0.f;
  if(tid < KT){
    float z = b2[tid];
    #pragma unroll 4
    for(int h = 0; h < HIDN; h++) z += hrow[h] * W2[h * KT + tid];
    th = (z > 0.f ? z : 0.f) + log1pf(expf(-fabsf(z)));   // softplus
  }
  thl[tid] = (tid < KT) ? th : -1e30f;
  __syncthreads();
  float m = thl[tid];
  #pragma unroll
  for(int s = 32; s >= 1; s >>= 1) m = fmaxf(m, __shfl_xor(m, s, 64));
  if((tid & 63) == 0) redm[tid >> 6] = m;
  __syncthreads();
  float mx = fmaxf(fmaxf(redm[0], redm[1]), fmaxf(redm[2], redm[3]));
  float e = (tid < KT) ? expf(th - mx) : 0.f;
  float s_ = e;
  #pragma unroll
  for(int s = 32; s >= 1; s >>= 1) s_ += __shfl_xor(s_, s, 64);
  if((tid & 63) == 0) reds[tid >> 6] = s_;
  __syncthreads();
  float sum = reds[0] + reds[1] + reds[2] + reds[3];
  if(tid < KP){
    short ts  = (tid < KT) ? f2bf(th / sumexp[tid]) : (short)0;  // theta / sum_v dis
    short tnb = (tid < KT) ? f2bf(e / sum) : (short)0;
    thetas_b[(long)b * KP + tid] = ts;
    thetan_b[(long)b * KP + tid] = tnb;
  }
  if(tid < KT) thetan_f[(long)b * KT + tid] = e / sum;
}

// ---------------- inner = rho @ alpha^T ; dis in topic-major (dis_t) + v-major (dis_v); sumexp ----------------
// (LDS stride 40 shorts = 80B rows -> bank stride 20, period-8: already 2-way, left as-is)
__global__ __launch_bounds__(256) void k_inner(const short* __restrict__ rho_p,
                                               const short* __restrict__ alpha_p,
                                               short* __restrict__ dis_t,
                                               short* __restrict__ dis_v,
                                               float* __restrict__ sumexp){
  __shared__ short As[128 * 40];
  __shared__ short Bs[64 * 40];
  __shared__ short tDis[128 * 72];
  __shared__ float sume_l[64];
  int tid = threadIdx.x, w = tid >> 6, lane = tid & 63, lm = lane & 15, q = lane >> 4;
  int v0 = blockIdx.x * 128, t0 = blockIdx.y * 64;
  if(tid < 64) sume_l[tid] = 0.f;
  __syncthreads();
  f32x4 acc[2][4];
  #pragma unroll
  for(int i = 0; i < 2; i++)
    #pragma unroll
    for(int j = 0; j < 4; j++) acc[i][j] = (f32x4){0.f,0.f,0.f,0.f};

  for(int h0 = 0; h0 < HP; h0 += 32){
    #pragma unroll
    for(int c0 = 0; c0 < 2; c0++){
      int c = tid + c0 * 256;
      int r = c >> 2, off = (c & 3) * 8;
      int vg = v0 + r;
      s8v v = {0,0,0,0,0,0,0,0};
      if(vg < V_) v = *(const s8v*)&rho_p[(long)vg * HP + h0 + off];
      *(s8v*)&As[r * 40 + off] = v;
    }
    {
      int r = tid >> 2, off = (tid & 3) * 8;
      int tg = t0 + r;
      s8v v = {0,0,0,0,0,0,0,0};
      if(tg < KT) v = *(const s8v*)&alpha_p[(long)tg * HP + h0 + off];
      *(s8v*)&Bs[r * 40 + off] = v;
    }
    __syncthreads();
    s8v af[2], bfr[4];
    #pragma unroll
    for(int i = 0; i < 2; i++) af[i]  = *(const s8v*)&As[(w * 32 + i * 16 + lm) * 40 + q * 8];
    #pragma unroll
    for(int j = 0; j < 4; j++) bfr[j] = *(const s8v*)&Bs[(j * 16 + lm) * 40 + q * 8];
    #pragma unroll
    for(int i = 0; i < 2; i++)
      #pragma unroll
      for(int j = 0; j < 4; j++)
        acc[i][j] = mfma16(af[i], bfr[j], acc[i][j]);
    __syncthreads();
  }
  // epilogue: dis into LDS tile (v-major, padded stride) + per-t exp sums
  #pragma unroll
  for(int i = 0; i < 2; i++)
    #pragma unroll
    for(int j = 0; j < 4; j++){
      int tg = t0 + j * 16 + lm;
      float s4 = 0.f;
      #pragma unroll
      for(int r = 0; r < 4; r++){
        int vloc = w * 32 + i * 16 + q * 4 + r;
        int vg = v0 + vloc;
        float x = acc[i][j][r];
        float e1 = __expf(x);  e1 = fminf(fmaxf(e1, 1e-30f), 1e10f);
        bool valid = (vg < V_) && (tg < KT);
        float dv = valid ? e1 : 0.f;
        tDis[vloc * 72 + (j * 16 + lm)] = f2bf(dv);
        s4 += dv;
      }
      s4 += __shfl_xor(s4, 16, 64);
      s4 += __shfl_xor(s4, 32, 64);
      if(q == 0) atomicAdd(&sume_l[j * 16 + lm], s4);
    }
  __syncthreads();
  // topic-major: dis_t[t][v], 16B contiguous in v  (guard: rows >= KP don't exist)
  for(int c = tid; c < 1024; c += 256){
    int t = c & 63, vch = c >> 6;          // vch 0..15
    int tg = t0 + t;
    if(tg < KP){
      s8v d;
      #pragma unroll
      for(int j = 0; j < 8; j++) d[j] = tDis[(vch * 8 + j) * 72 + t];
      *(s8v*)&dis_t[(long)tg * VP + v0 + vch * 8] = d;
    }
  }
  // v-major: dis_v[v][t], 16B contiguous in t  (guard: t0=192 block only owns cols 192..223)
  for(int c = tid; c < 1024; c += 256){
    int r = c >> 3, tch = (c & 7) * 8;     // r 0..127, tch 0..56
    if(t0 + tch < KP)
      *(s8v*)&dis_v[(long)(v0 + r) * KP + t0 + tch] = *(const s8v*)&tDis[r * 72 + tch];
  }
  if(tid < 64 && (t0 + tid) < KT) atomicAdd(&sumexp[t0 + tid], sume_l[tid]);
}

// ---------------- fused consumer: den/recon GEMMs + forward/tm reductions ----------------
// grid = (NVB, 4). Theta tiles staged K-MAJOR: LDS granule = kg*16 + doc, so the
// 14 b128 fragment reads per chunk hit bank lm*4%32 (2-way free) instead of the
// 448B-row-stride 8-way conflict. Global source address pre-permuted per lane.
__global__ __launch_bounds__(256) void k_consumer(const short* __restrict__ dis_v,
                                                  const short* __restrict__ thetan_b,
                                                  const short* __restrict__ thetas_b,
                                                  const short* __restrict__ bows_b,
                                                  float* __restrict__ fwd_part,
                                                  float* __restrict__ tm_acc){
  __shared__ short tTN[2][16 * KP];   // k-major: [kg 0..27][doc 0..15] granules
  __shared__ short tTS[2][16 * KP];
  __shared__ float fwd_l[128];
  __shared__ float tm_l;
  int tid = threadIdx.x;
  if(tid < 128) fwd_l[tid] = 0.f;
  if(tid == 0) tm_l = 0.f;
  int w = tid >> 6, lane = tid & 63, lm = lane & 15, q = lane >> 4;
  int bx = blockIdx.x, by = blockIdx.y;
  int v0 = bx * 64;
  int vrow = v0 + w * 16 + lm;
  s8v disf[7];
  #pragma unroll
  for(int i = 0; i < 7; i++)
    disf[i] = *(const s8v*)&dis_v[(long)vrow * KP + i * 32 + q * 8];

  auto STAGE = [&](int buf, int cb){
    // inst j=w covers granules tid (kg=tid>>4, doc=tid&15); inst j=w+4 covers tid+256.
    long base = (long)cb * 16 * KP + (tid & 15) * KP + (tid >> 4) * 8;
    load_lds16(&thetan_b[base], &tTN[buf][w * 512]);
    load_lds16(&thetas_b[base], &tTS[buf][w * 512]);
    if(w < 3){
      load_lds16(&thetan_b[base + 128], &tTN[buf][(w + 4) * 512]);
      load_lds16(&thetas_b[base + 128], &tTS[buf][(w + 4) * 512]);
    }
  };

  int cb0 = by * 8;
  STAGE(0, cb0);
  __syncthreads();             // vmcnt(0) drain: tile 0 resident; fwd_l init visible
  float tmreg = 0.f;
  int cur = 0;
  for(int cb = cb0; cb < cb0 + 8; cb++){
    int b0 = cb * 16;
    if(cb + 1 < cb0 + 8) STAGE(cur ^ 1, cb + 1);   // async prefetch overlaps compute
    // bows load early: global latency hides under the MFMA chain
    short4 bw4 = *(const short4*)&bows_b[(long)(b0 + lm) * VP + v0 + w * 16 + q * 4];
    f32x4 aD = {0.f,0.f,0.f,0.f}, aR = {0.f,0.f,0.f,0.f};
    #pragma unroll
    for(int i = 0; i < 7; i++){
      int off = (i * 4 + q) * 128 + lm * 8;        // k-major: bank = lm*4%32, 2-way free
      s8v tn = *(const s8v*)&tTN[cur][off];
      s8v ts = *(const s8v*)&tTS[cur][off];
      aD = mfma16(disf[i], tn, aD);
      aR = mfma16(disf[i], ts, aR);
    }
    int bg = b0 + lm;
    float fwd_p = 0.f;
    #pragma unroll
    for(int r = 0; r < 4; r++){
      float bv = __uint_as_float(((unsigned)(unsigned short)(&bw4.x)[r]) << 16);
      float den = aD[r] + 1e-30f;
      float rec = aR[r];
      fwd_p += bv * __builtin_amdgcn_rcpf(den);   // num == 1 (cost*dis == 1)
      float lg = bv < 1.5f ? 0.f : (bv < 2.5f ? 0.69314718056f :
                 (bv < 3.5f ? 1.79175946923f : 3.17805383035f));
      tmreg += bv * __logf(rec + 1e-10f) - rec - lg;
    }
    fwd_p += __shfl_xor(fwd_p, 16, 64); fwd_p += __shfl_xor(fwd_p, 32, 64);
    if(q == 0) atomicAdd(&fwd_l[bg - by * 128], fwd_p);
    __syncthreads();           // prefetch landed; all waves done reading cur
    cur ^= 1;
  }
  #pragma unroll
  for(int s = 32; s >= 1; s >>= 1) tmreg += __shfl_xor(tmreg, s, 64);
  if(lane == 0) atomicAdd(&tm_l, tmreg);
  __syncthreads();
  if(tid < 128) fwd_part[(long)(by * 128 + tid) * NVB + bx] = fwd_l[tid];
  if(tid == 0) atomicAdd(tm_acc, tm_l);
}

// ---------------- colsum = bows@dis (split-K, atomic) ----------------
// Ring-3 + counted vmcnt + k-major LDS (same conflict fix as k_gemm1).
__global__ __launch_bounds__(256) void k_colsum(const short* __restrict__ bows_b,
                                                const short* __restrict__ dis_t,
                                                float* __restrict__ colsum_acc){
  __shared__ short As[3][128 * 32];
  __shared__ short BsD[3][64 * 32];
  int tid = threadIdx.x, w = tid >> 6, lane = tid & 63, lm = lane & 15, q = lane >> 4;
  int f = blockIdx.x;                       // 736 = 8 * 92
  int lid = (f & 7) * 92 + (f >> 3);
  int z = lid >> 4, rem = lid & 15;         // 16 blocks per k-slice
  int by = rem >> 2, bx = rem & 3;
  int m0 = bx * 128, t0 = by * 64;
  long kstart = (long)z * 1088;
  int nt = 34;                              // 1088/32, uniform (46*1088 == VP)
  int rsub = lane & 15;          // k-major lane decomposition
  int kl = (lane >> 4) * 8;
  int rA0 = m0 + w * 16 + rsub;
  int rA1 = m0 + (w + 4) * 16 + rsub;
  int tB = t0 + w * 16 + rsub; if(tB > KP - 1) tB = KP - 1;   // rows >= KT are zeros
  f32x4 accD[2][4];
  #pragma unroll
  for(int i = 0; i < 2; i++)
    #pragma unroll
    for(int j = 0; j < 4; j++) accD[i][j] = (f32x4){0.f,0.f,0.f,0.f};

  auto STAGE = [&](int buf, int t){
    long kb = kstart + ((long)t << 5);
    load_lds16(&bows_b[(long)rA0 * VP + kb + kl], &As[buf][w * 512]);
    load_lds16(&bows_b[(long)rA1 * VP + kb + kl], &As[buf][(w + 4) * 512]);
    load_lds16(&dis_t[(long)tB * VP + kb + kl], &BsD[buf][w * 512]);
  };

  STAGE(0, 0);
  STAGE(1, 1);
  int cb = 0, sb = 2;
  for(int t = 0; t < nt; t++){
    if(t < nt - 1) asm volatile("s_waitcnt vmcnt(3)\n\ts_barrier" ::: "memory");
    else           asm volatile("s_waitcnt vmcnt(0)\n\ts_barrier" ::: "memory");
    if(t + 2 < nt) STAGE(sb, t + 2);
    s8v af[2], bd[4];
    #pragma unroll
    for(int i = 0; i < 2; i++) af[i] = *(const s8v*)&As[cb][(w * 2 + i) * 512 + q * 128 + lm * 8];
    #pragma unroll
    for(int j = 0; j < 4; j++) bd[j] = *(const s8v*)&BsD[cb][j * 512 + q * 128 + lm * 8];
    #pragma unroll
    for(int i = 0; i < 2; i++)
      #pragma unroll
      for(int j = 0; j < 4; j++)
        accD[i][j] = mfma16(af[i], bd[j], accD[i][j]);
    cb = (cb == 2) ? 0 : cb + 1;
    sb = (sb == 2) ? 0 : sb + 1;
  }
  #pragma unroll
  for(int i = 0; i < 2; i++)
    #pragma unroll
    for(int j = 0; j < 4; j++){
      int doc = m0 + w * 32 + i * 16 + q * 4;
      int tg = t0 + j * 16 + lm;
      if(tg < KT){
        #pragma unroll
        for(int r = 0; r < 4; r++)
          atomicAdd(&colsum_acc[(long)(doc + r) * KT + tg], accD[i][j][r]);
      }
    }
}

// ---------------- per-doc backward + forward finalize ----------------
__global__ __launch_bounds__(64) void k_bwd(const float* __restrict__ colsum_acc,
                                            const float* __restrict__ thn_f,
                                            const float* __restrict__ fwd_part,
                                            const float* __restrict__ ntok_acc,
                                            float* __restrict__ bwd_pd,
                                            float* __restrict__ fwd_pd){
  int b = blockIdx.x, lane = threadIdx.x;
  float s = 0.f;
  for(int t = lane; t < KT; t += 64)
    s += thn_f[(long)b * KT + t] * __builtin_amdgcn_rcpf(colsum_acc[(long)b * KT + t] + 1e-30f);
  float fp = 0.f;
  for(int p = lane; p < NVB; p += 64) fp += fwd_part[(long)b * NVB + p];
  #pragma unroll
  for(int k = 32; k >= 1; k >>= 1){ s += __shfl_xor(s, k, 64); fp += __shfl_xor(fp, k, 64); }
  if(lane == 0){
    float nt = ntok_acc[b];
    bwd_pd[b] = s * nt;                     // A[b,k] == ntok[b] (bows @ 1)
    fwd_pd[b] = fp / fmaxf(nt, 1.f);
  }
}

// ---------------- final reduce + 3 outputs ----------------
__global__ __launch_bounds__(512) void k_final(const float* __restrict__ bwd_pd,
                                               const float* __restrict__ fwd_pd,
                                               const float* __restrict__ ntok_acc,
                                               const float* __restrict__ tm_acc,
                                               float* __restrict__ out){
  __shared__ float rf[8], rb[8];
  int tid = threadIdx.x, w = tid >> 6, lane = tid & 63;
  bool valid = ntok_acc[tid] > 0.f;
  float fw = valid ? fwd_pd[tid] : 0.f;
  float bw = valid ? bwd_pd[tid] : 0.f;
  #pragma unroll
  for(int s = 32; s >= 1; s >>= 1){ fw += __shfl_xor(fw, s, 64); bw += __shfl_xor(bw, s, 64); }
  if(lane == 0){ rf[w] = fw; rb[w] = bw; }
  __syncthreads();
  if(tid == 0){
    float F = 0.f, Bw = 0.f;
    #pragma unroll
    for(int i = 0; i < 8; i++){ F += rf[i]; Bw += rb[i]; }
    out[0] = 1.0f * (-tm_acc[0] / (float)B_);  // EPSILON * tm
    out[1] = 0.5f * F;                         // BETA * forward
    out[2] = 0.5f * Bw;                        // (1-BETA) * backward
  }
}

extern "C" void kernel_launch(void* const* d_in, const int* in_sizes, int n_in,
                              void* d_out, int out_size, void* d_ws, size_t ws_size,
                              hipStream_t stream){
  const float* bows  = (const float*)d_in[0];
  const float* rho   = (const float*)d_in[1];
  const float* alpha = (const float*)d_in[2];
  const float* W1    = (const float*)d_in[3];
  const float* b1    = (const float*)d_in[4];
  const float* W2    = (const float*)d_in[5];
  const float* b2    = (const float*)d_in[6];
  float* out = (float*)d_out;
  char* ws = (char*)d_ws;
  size_t o = 0;
  auto alloc = [&](size_t bytes) -> char* {
    char* p = ws + o; o = (o + bytes + 255) & ~(size_t)255; return p;
  };
  // zeroed region (contiguous, zeroed every launch)
  float* hid_acc    = (float*)alloc((size_t)B_ * HIDN * 4);
  float* colsum_acc = (float*)alloc((size_t)B_ * KT * 4);
  float* sumexp     = (float*)alloc(KP * 4);
  float* ntok_acc   = (float*)alloc(B_ * 4);
  float* tm_acc     = (float*)alloc(256);
  float* bwd_pd     = (float*)alloc(B_ * 4);
  float* fwd_pd     = (float*)alloc(B_ * 4);
  size_t zbytes = o;
  // scratch (fully written before read)
  short* bows_b   = (short*)alloc((size_t)B_ * VP * 2);
  short* W1t      = (short*)alloc((size_t)HIDN * VP * 2);
  short* rho_p    = (short*)alloc((size_t)V_ * HP * 2);
  short* alpha_p  = (short*)alloc((size_t)KT * HP * 2);
  short* thetas_b = (short*)alloc((size_t)B_ * KP * 2);
  short* thetan_b = (short*)alloc((size_t)B_ * KP * 2);
  float* thetan_f = (float*)alloc((size_t)B_ * KT * 4);
  short* dis_t    = (short*)alloc((size_t)KP * VP * 2);
  short* dis_v    = (short*)alloc((size_t)VP * KP * 2);
  float* fwd_part = (float*)alloc((size_t)B_ * NVB * 4);

  kzero<<<256, 256, 0, stream>>>((float*)ws, (long)(zbytes / 4));
  k_bows<<<dim3(25, 512), 256, 0, stream>>>(bows, bows_b, ntok_acc);
  k_transW1<<<dim3(VP / 32, HIDN / 32), 256, 0, stream>>>(W1, W1t);
  kconvpad<<<V_, HP, 0, stream>>>(rho, rho_p, HH, HP);
  kconvpad<<<KT, HP, 0, stream>>>(alpha, alpha_p, HH, HP);
  k_inner<<<dim3(VP / 128, 4), 256, 0, stream>>>(rho_p, alpha_p, dis_t, dis_v, sumexp);
  k_gemm1<<<dim3(896), 256, 0, stream>>>(bows_b, W1t, hid_acc);
  k_theta<<<B_, 256, 0, stream>>>(hid_acc, b1, W2, b2, sumexp, thetas_b, thetan_b, thetan_f);
  k_consumer<<<dim3(NVB, 4), 256, 0, stream>>>(dis_v, thetan_b, thetas_b, bows_b,
                                               fwd_part, tm_acc);
  k_colsum<<<dim3(736), 256, 0, stream>>>(bows_b, dis_t, colsum_acc);
  k_bwd<<<B_, 64, 0, stream>>>(colsum_acc, thetan_f, fwd_part, ntok_acc, bwd_pd, fwd_pd);
  k_final<<<1, 512, 0, stream>>>(bwd_pd, fwd_pd, ntok_acc, tm_acc, out);
}

// Round 5
// 749.092 us; speedup vs baseline: 1.0840x; 1.0840x over previous
//
#include <hip/hip_runtime.h>

#define B_    512
#define V_    50000
#define VP    50048   // padded vocab (64*782)
#define KT    200     // topics
#define HH    300     // embedding dim
#define HIDN  800     // hidden
#define KP    224     // padded topic dim (7*32)
#define HP    320     // padded embedding dim (10*32)
#define NVB   782     // VP/64 v-blocks (consumer partials per doc)
#define ZG1   32      // gemm1 split-K slices
#define ZCS   46      // colsum split-K slices (46*1088 = VP)

typedef __attribute__((ext_vector_type(4))) float  f32x4;
typedef __attribute__((ext_vector_type(8))) short  s8v;
typedef __attribute__((ext_vector_type(8))) __bf16 bf16x8;
typedef unsigned int u32;

static __device__ __forceinline__ f32x4 mfma16(s8v a, s8v b, f32x4 c){
  return __builtin_amdgcn_mfma_f32_16x16x32_bf16(
      __builtin_bit_cast(bf16x8, a), __builtin_bit_cast(bf16x8, b), c, 0, 0, 0);
}
static __device__ __forceinline__ short f2bf(float f){
  unsigned u = __float_as_uint(f);
  u = (u + 0x7fffu + ((u >> 16) & 1u)) >> 16;
  return (short)u;
}
// async global->LDS, 16B per lane; LDS dest = wave-uniform base + lane*16
static __device__ __forceinline__ void load_lds16(const short* g, short* lds){
  __builtin_amdgcn_global_load_lds(
      (const __attribute__((address_space(1))) u32*)g,
      (__attribute__((address_space(3))) u32*)lds, 16, 0, 0);
}

// ---------------- zero init ----------------
__global__ void kzero(float* p, long n){
  long i = blockIdx.x * (long)blockDim.x + threadIdx.x;
  long st = (long)gridDim.x * blockDim.x;
  for(; i < n; i += st) p[i] = 0.f;
}

// ---------------- bows fp32 -> bf16 (rows padded to VP) + per-doc token counts ----------------
__global__ __launch_bounds__(256) void k_bows(const float* __restrict__ src,
                                              short* __restrict__ dst,
                                              float* __restrict__ ntok_acc){
  __shared__ float r4[4];
  int b = blockIdx.y;
  int c = blockIdx.x * 256 + threadIdx.x;          // chunk of 8 shorts
  int lane = threadIdx.x & 63, w = threadIdx.x >> 6;
  float s = 0.f;
  if(c < VP / 8){
    int v = c * 8;
    s8v o = {0,0,0,0,0,0,0,0};
    if(v + 8 <= V_){
      float4 a = *(const float4*)&src[(long)b * V_ + v];
      float4 d = *(const float4*)&src[(long)b * V_ + v + 4];
      o[0]=f2bf(a.x); o[1]=f2bf(a.y); o[2]=f2bf(a.z); o[3]=f2bf(a.w);
      o[4]=f2bf(d.x); o[5]=f2bf(d.y); o[6]=f2bf(d.z); o[7]=f2bf(d.w);
      s = a.x + a.y + a.z + a.w + d.x + d.y + d.z + d.w;
    }
    *(s8v*)&dst[(long)b * VP + v] = o;
  }
  #pragma unroll
  for(int k = 32; k >= 1; k >>= 1) s += __shfl_xor(s, k, 64);
  if(lane == 0) r4[w] = s;
  __syncthreads();
  if(threadIdx.x == 0) atomicAdd(&ntok_acc[b], r4[0] + r4[1] + r4[2] + r4[3]);
}

// ---------------- W1 (V x HIDN fp32) -> W1t (HIDN x VP bf16, transposed) ----------------
__global__ __launch_bounds__(256) void k_transW1(const float* __restrict__ W1,
                                                 short* __restrict__ W1t){
  __shared__ float tile[32][33];
  int v0 = blockIdx.x * 32, n0 = blockIdx.y * 32;
  int tid = threadIdx.x;
  int r = tid >> 3, c4 = (tid & 7) * 4;
  float4 val = {0.f,0.f,0.f,0.f};
  int v = v0 + r;
  if(v < V_) val = *(const float4*)&W1[(long)v * HIDN + n0 + c4];
  tile[r][c4+0] = val.x; tile[r][c4+1] = val.y; tile[r][c4+2] = val.z; tile[r][c4+3] = val.w;
  __syncthreads();
  short4 o;
  o.x = f2bf(tile[c4+0][r]); o.y = f2bf(tile[c4+1][r]);
  o.z = f2bf(tile[c4+2][r]); o.w = f2bf(tile[c4+3][r]);
  *(short4*)&W1t[(long)(n0 + r) * VP + v0 + c4] = o;
}

// ---------------- fp32 -> bf16 with row padding (blockDim = kpad) ----------------
__global__ void kconvpad(const float* __restrict__ src, short* __restrict__ dst,
                         int kin, int kpad){
  int r = blockIdx.x, c = threadIdx.x;
  float v = (c < kin) ? src[(long)r * kin + c] : 0.f;
  dst[(long)r * kpad + c] = f2bf(v);
}

// ---------------- GEMM1: hid_part[z] = bows @ W1 (split-K, NO atomics) ----------------
// R2-measured-best K-loop (row-major LDS, dbuf-2, __syncthreads drain) + XCD z-major
// swizzle (keeps one k-slice's A/B panels per XCD L2). Epilogue: plain coalesced
// fp32 stores into per-slice partial buffer; k_theta reduces the 32 slices.
// (Previous atomic epilogue: 14.7M device-scope RMW into 1.6MB, 32-way contention.)
__global__ __launch_bounds__(256) void k_gemm1(const short* __restrict__ Ab,
                                               const short* __restrict__ Bb,
                                               float* __restrict__ Cpart){
  __shared__ short As[2][128 * 32];
  __shared__ short Bs[2][128 * 32];
  int tid = threadIdx.x, w = tid >> 6, lane = tid & 63, lm = lane & 15, q = lane >> 4;
  int f = blockIdx.x;                       // 896 = 8 XCDs * 112
  int lid = (f & 7) * 112 + (f >> 3);       // logical id, z-major
  int z = lid / 28, rem = lid % 28;         // 28 = 7 n-blocks * 4 m-blocks per k-slice
  int by = rem >> 2, bx = rem & 3;
  int m0 = bx * 128, n0 = by * 128;
  long kstart = (long)z * 1568;
  long kend = kstart + 1568; if(kend > VP) kend = VP;
  int rsub = lane >> 2;          // 0..15 within 16-row chunk
  int kl = (lane & 3) * 8;       // shorts within 32-short row (4-lane quads contiguous)
  int rA0 = m0 + w * 16 + rsub;
  int rA1 = m0 + (w + 4) * 16 + rsub;
  int nB0 = n0 + w * 16 + rsub;       if(nB0 > HIDN - 1) nB0 = HIDN - 1;
  int nB1 = n0 + (w + 4) * 16 + rsub; if(nB1 > HIDN - 1) nB1 = HIDN - 1;
  f32x4 acc[2][8];
  #pragma unroll
  for(int i = 0; i < 2; i++)
    #pragma unroll
    for(int j = 0; j < 8; j++) acc[i][j] = (f32x4){0.f,0.f,0.f,0.f};

  auto STAGE = [&](int buf, long kb){
    load_lds16(&Ab[(long)rA0 * VP + kb + kl], &As[buf][w * 512]);
    load_lds16(&Ab[(long)rA1 * VP + kb + kl], &As[buf][(w + 4) * 512]);
    load_lds16(&Bb[(long)nB0 * VP + kb + kl], &Bs[buf][w * 512]);
    load_lds16(&Bb[(long)nB1 * VP + kb + kl], &Bs[buf][(w + 4) * 512]);
  };

  STAGE(0, kstart);
  __syncthreads();
  int cur = 0;
  for(long kb = kstart; kb < kend; kb += 32){
    if(kb + 32 < kend) STAGE(cur ^ 1, kb + 32);
    s8v af[2], bfr[8];
    #pragma unroll
    for(int i = 0; i < 2; i++) af[i]  = *(const s8v*)&As[cur][(w * 32 + i * 16 + lm) * 32 + q * 8];
    #pragma unroll
    for(int j = 0; j < 8; j++) bfr[j] = *(const s8v*)&Bs[cur][(j * 16 + lm) * 32 + q * 8];
    #pragma unroll
    for(int i = 0; i < 2; i++)
      #pragma unroll
      for(int j = 0; j < 8; j++)
        acc[i][j] = mfma16(af[i], bfr[j], acc[i][j]);
    __syncthreads();
    cur ^= 1;
  }
  float* cp = Cpart + (long)z * B_ * HIDN;
  #pragma unroll
  for(int i = 0; i < 2; i++)
    #pragma unroll
    for(int j = 0; j < 8; j++){
      int gm = m0 + w * 32 + i * 16 + q * 4;
      int gn = n0 + j * 16 + lm;
      if(gn < HIDN){
        #pragma unroll
        for(int r = 0; r < 4; r++) cp[(long)(gm + r) * HIDN + gn] = acc[i][j][r];
      }
    }
}

// ---------------- theta: reduce hid partials + relu -> @W2 -> softplus -> softmax ----------------
__global__ __launch_bounds__(256) void k_theta(const float* __restrict__ hid_part,
                                               const float* __restrict__ b1,
                                               const float* __restrict__ W2,
                                               const float* __restrict__ b2,
                                               const float* __restrict__ sumexp,
                                               short* __restrict__ thetas_b,
                                               short* __restrict__ thetan_b,
                                               float* __restrict__ thetan_f){
  __shared__ float hrow[HIDN];
  __shared__ float thl[256];
  __shared__ float redm[4], reds[4];
  int b = blockIdx.x, tid = threadIdx.x;
  for(int h = tid; h < HIDN; h += 256){
    float x = b1[h];
    #pragma unroll 8
    for(int z = 0; z < ZG1; z++) x += hid_part[((long)z * B_ + b) * HIDN + h];
    hrow[h] = x > 0.f ? x : 0.f;
  }
  __syncthreads();
  float th = 0.f;
  if(tid < KT){
    float zz = b2[tid];
    #pragma unroll 4
    for(int h = 0; h < HIDN; h++) zz += hrow[h] * W2[h * KT + tid];
    th = (zz > 0.f ? zz : 0.f) + log1pf(expf(-fabsf(zz)));   // softplus
  }
  thl[tid] = (tid < KT) ? th : -1e30f;
  __syncthreads();
  float m = thl[tid];
  #pragma unroll
  for(int s = 32; s >= 1; s >>= 1) m = fmaxf(m, __shfl_xor(m, s, 64));
  if((tid & 63) == 0) redm[tid >> 6] = m;
  __syncthreads();
  float mx = fmaxf(fmaxf(redm[0], redm[1]), fmaxf(redm[2], redm[3]));
  float e = (tid < KT) ? expf(th - mx) : 0.f;
  float s_ = e;
  #pragma unroll
  for(int s = 32; s >= 1; s >>= 1) s_ += __shfl_xor(s_, s, 64);
  if((tid & 63) == 0) reds[tid >> 6] = s_;
  __syncthreads();
  float sum = reds[0] + reds[1] + reds[2] + reds[3];
  if(tid < KP){
    short ts  = (tid < KT) ? f2bf(th / sumexp[tid]) : (short)0;  // theta / sum_v dis
    short tnb = (tid < KT) ? f2bf(e / sum) : (short)0;
    thetas_b[(long)b * KP + tid] = ts;
    thetan_b[(long)b * KP + tid] = tnb;
  }
  if(tid < KT) thetan_f[(long)b * KT + tid] = e / sum;
}

// ---------------- inner = rho @ alpha^T ; dis in topic-major (dis_t) + v-major (dis_v); sumexp ----------------
__global__ __launch_bounds__(256) void k_inner(const short* __restrict__ rho_p,
                                               const short* __restrict__ alpha_p,
                                               short* __restrict__ dis_t,
                                               short* __restrict__ dis_v,
                                               float* __restrict__ sumexp){
  __shared__ short As[128 * 40];
  __shared__ short Bs[64 * 40];
  __shared__ short tDis[128 * 72];
  __shared__ float sume_l[64];
  int tid = threadIdx.x, w = tid >> 6, lane = tid & 63, lm = lane & 15, q = lane >> 4;
  int v0 = blockIdx.x * 128, t0 = blockIdx.y * 64;
  if(tid < 64) sume_l[tid] = 0.f;
  __syncthreads();
  f32x4 acc[2][4];
  #pragma unroll
  for(int i = 0; i < 2; i++)
    #pragma unroll
    for(int j = 0; j < 4; j++) acc[i][j] = (f32x4){0.f,0.f,0.f,0.f};

  for(int h0 = 0; h0 < HP; h0 += 32){
    #pragma unroll
    for(int c0 = 0; c0 < 2; c0++){
      int c = tid + c0 * 256;
      int r = c >> 2, off = (c & 3) * 8;
      int vg = v0 + r;
      s8v v = {0,0,0,0,0,0,0,0};
      if(vg < V_) v = *(const s8v*)&rho_p[(long)vg * HP + h0 + off];
      *(s8v*)&As[r * 40 + off] = v;
    }
    {
      int r = tid >> 2, off = (tid & 3) * 8;
      int tg = t0 + r;
      s8v v = {0,0,0,0,0,0,0,0};
      if(tg < KT) v = *(const s8v*)&alpha_p[(long)tg * HP + h0 + off];
      *(s8v*)&Bs[r * 40 + off] = v;
    }
    __syncthreads();
    s8v af[2], bfr[4];
    #pragma unroll
    for(int i = 0; i < 2; i++) af[i]  = *(const s8v*)&As[(w * 32 + i * 16 + lm) * 40 + q * 8];
    #pragma unroll
    for(int j = 0; j < 4; j++) bfr[j] = *(const s8v*)&Bs[(j * 16 + lm) * 40 + q * 8];
    #pragma unroll
    for(int i = 0; i < 2; i++)
      #pragma unroll
      for(int j = 0; j < 4; j++)
        acc[i][j] = mfma16(af[i], bfr[j], acc[i][j]);
    __syncthreads();
  }
  // epilogue: dis into LDS tile (v-major, padded stride) + per-t exp sums
  #pragma unroll
  for(int i = 0; i < 2; i++)
    #pragma unroll
    for(int j = 0; j < 4; j++){
      int tg = t0 + j * 16 + lm;
      float s4 = 0.f;
      #pragma unroll
      for(int r = 0; r < 4; r++){
        int vloc = w * 32 + i * 16 + q * 4 + r;
        int vg = v0 + vloc;
        float x = acc[i][j][r];
        float e1 = __expf(x);  e1 = fminf(fmaxf(e1, 1e-30f), 1e10f);
        bool valid = (vg < V_) && (tg < KT);
        float dv = valid ? e1 : 0.f;
        tDis[vloc * 72 + (j * 16 + lm)] = f2bf(dv);
        s4 += dv;
      }
      s4 += __shfl_xor(s4, 16, 64);
      s4 += __shfl_xor(s4, 32, 64);
      if(q == 0) atomicAdd(&sume_l[j * 16 + lm], s4);
    }
  __syncthreads();
  // topic-major: dis_t[t][v], 16B contiguous in v  (guard: rows >= KP don't exist)
  for(int c = tid; c < 1024; c += 256){
    int t = c & 63, vch = c >> 6;          // vch 0..15
    int tg = t0 + t;
    if(tg < KP){
      s8v d;
      #pragma unroll
      for(int j = 0; j < 8; j++) d[j] = tDis[(vch * 8 + j) * 72 + t];
      *(s8v*)&dis_t[(long)tg * VP + v0 + vch * 8] = d;
    }
  }
  // v-major: dis_v[v][t], 16B contiguous in t  (guard: t0=192 block only owns cols 192..223)
  for(int c = tid; c < 1024; c += 256){
    int r = c >> 3, tch = (c & 7) * 8;     // r 0..127, tch 0..56
    if(t0 + tch < KP)
      *(s8v*)&dis_v[(long)(v0 + r) * KP + t0 + tch] = *(const s8v*)&tDis[r * 72 + tch];
  }
  if(tid < 64 && (t0 + tid) < KT) atomicAdd(&sumexp[t0 + tid], sume_l[tid]);
}

// ---------------- fused consumer: den/recon GEMMs + forward/tm reductions ----------------
// grid = (NVB, 4). Theta tiles (16 docs x KP, contiguous 7168B in global) staged into
// LDS via async global_load_lds (R1 contiguous pattern), double-buffered.
__global__ __launch_bounds__(256) void k_consumer(const short* __restrict__ dis_v,
                                                  const short* __restrict__ thetan_b,
                                                  const short* __restrict__ thetas_b,
                                                  const short* __restrict__ bows_b,
                                                  float* __restrict__ fwd_part,
                                                  float* __restrict__ tm_acc){
  __shared__ short tTN[2][16 * KP];   // 16 docs x 224 topics, 448B rows (7168B/buf)
  __shared__ short tTS[2][16 * KP];
  __shared__ float fwd_l[128];
  __shared__ float tm_l;
  int tid = threadIdx.x;
  if(tid < 128) fwd_l[tid] = 0.f;
  if(tid == 0) tm_l = 0.f;
  int w = tid >> 6, lane = tid & 63, lm = lane & 15, q = lane >> 4;
  int bx = blockIdx.x, by = blockIdx.y;
  int v0 = bx * 64;
  int vrow = v0 + w * 16 + lm;
  s8v disf[7];
  #pragma unroll
  for(int i = 0; i < 7; i++)
    disf[i] = *(const s8v*)&dis_v[(long)vrow * KP + i * 32 + q * 8];

  auto STAGE = [&](int buf, int cb){
    long base = (long)cb * 16 * KP;       // shorts; tile is contiguous in global
    load_lds16(&thetan_b[base + tid * 8], &tTN[buf][tid * 8]);
    load_lds16(&thetas_b[base + tid * 8], &tTS[buf][tid * 8]);
    if(tid < 192){
      load_lds16(&thetan_b[base + 2048 + tid * 8], &tTN[buf][2048 + tid * 8]);
      load_lds16(&thetas_b[base + 2048 + tid * 8], &tTS[buf][2048 + tid * 8]);
    }
  };

  int cb0 = by * 8;
  STAGE(0, cb0);
  __syncthreads();             // vmcnt(0) drain: tile 0 resident; fwd_l init visible
  float tmreg = 0.f;
  int cur = 0;
  for(int cb = cb0; cb < cb0 + 8; cb++){
    int b0 = cb * 16;
    if(cb + 1 < cb0 + 8) STAGE(cur ^ 1, cb + 1);   // async prefetch overlaps compute
    // bows load early: global latency hides under the MFMA chain
    short4 bw4 = *(const short4*)&bows_b[(long)(b0 + lm) * VP + v0 + w * 16 + q * 4];
    f32x4 aD = {0.f,0.f,0.f,0.f}, aR = {0.f,0.f,0.f,0.f};
    #pragma unroll
    for(int i = 0; i < 7; i++){
      int off = lm * KP + i * 32 + q * 8;
      s8v tn = *(const s8v*)&tTN[cur][off];
      s8v ts = *(const s8v*)&tTS[cur][off];
      aD = mfma16(disf[i], tn, aD);
      aR = mfma16(disf[i], ts, aR);
    }
    int bg = b0 + lm;
    float fwd_p = 0.f;
    #pragma unroll
    for(int r = 0; r < 4; r++){
      float bv = __uint_as_float(((unsigned)(unsigned short)(&bw4.x)[r]) << 16);
      float den = aD[r] + 1e-30f;
      float rec = aR[r];
      fwd_p += bv * __builtin_amdgcn_rcpf(den);   // num == 1 (cost*dis == 1)
      float lg = bv < 1.5f ? 0.f : (bv < 2.5f ? 0.69314718056f :
                 (bv < 3.5f ? 1.79175946923f : 3.17805383035f));
      tmreg += bv * __logf(rec + 1e-10f) - rec - lg;
    }
    fwd_p += __shfl_xor(fwd_p, 16, 64); fwd_p += __shfl_xor(fwd_p, 32, 64);
    if(q == 0) atomicAdd(&fwd_l[bg - by * 128], fwd_p);
    __syncthreads();           // prefetch landed; all waves done reading cur
    cur ^= 1;
  }
  #pragma unroll
  for(int s = 32; s >= 1; s >>= 1) tmreg += __shfl_xor(tmreg, s, 64);
  if(lane == 0) atomicAdd(&tm_l, tmreg);
  __syncthreads();
  if(tid < 128) fwd_part[(long)(by * 128 + tid) * NVB + bx] = fwd_l[tid];
  if(tid == 0) atomicAdd(tm_acc, tm_l);
}

// ---------------- colsum partials = bows@dis per k-slice (NO atomics) ----------------
// R2-measured-best K-loop + XCD z-swizzle; plain stores to colsum_part[z][b][t].
__global__ __launch_bounds__(256) void k_colsum(const short* __restrict__ bows_b,
                                                const short* __restrict__ dis_t,
                                                float* __restrict__ Cpart){
  __shared__ short As[2][128 * 32];
  __shared__ short BsD[2][64 * 32];
  int tid = threadIdx.x, w = tid >> 6, lane = tid & 63, lm = lane & 15, q = lane >> 4;
  int f = blockIdx.x;                       // 736 = 8 * 92
  int lid = (f & 7) * 92 + (f >> 3);
  int z = lid >> 4, rem = lid & 15;         // 16 blocks per k-slice
  int by = rem >> 2, bx = rem & 3;
  int m0 = bx * 128, t0 = by * 64;
  long kstart = (long)z * 1088;
  long kend = kstart + 1088;                // uniform: 46*1088 == VP
  int rsub = lane >> 2;
  int kl = (lane & 3) * 8;
  int rA0 = m0 + w * 16 + rsub;
  int rA1 = m0 + (w + 4) * 16 + rsub;
  int tB = t0 + w * 16 + rsub; if(tB > KP - 1) tB = KP - 1;   // rows >= KT are zeros
  f32x4 accD[2][4];
  #pragma unroll
  for(int i = 0; i < 2; i++)
    #pragma unroll
    for(int j = 0; j < 4; j++) accD[i][j] = (f32x4){0.f,0.f,0.f,0.f};

  auto STAGE = [&](int buf, long kb){
    load_lds16(&bows_b[(long)rA0 * VP + kb + kl], &As[buf][w * 512]);
    load_lds16(&bows_b[(long)rA1 * VP + kb + kl], &As[buf][(w + 4) * 512]);
    load_lds16(&dis_t[(long)tB * VP + kb + kl], &BsD[buf][w * 512]);
  };

  STAGE(0, kstart);
  __syncthreads();
  int cur = 0;
  for(long kb = kstart; kb < kend; kb += 32){
    if(kb + 32 < kend) STAGE(cur ^ 1, kb + 32);
    s8v af[2], bd[4];
    #pragma unroll
    for(int i = 0; i < 2; i++) af[i] = *(const s8v*)&As[cur][(w * 32 + i * 16 + lm) * 32 + q * 8];
    #pragma unroll
    for(int j = 0; j < 4; j++) bd[j] = *(const s8v*)&BsD[cur][(j * 16 + lm) * 32 + q * 8];
    #pragma unroll
    for(int i = 0; i < 2; i++)
      #pragma unroll
      for(int j = 0; j < 4; j++)
        accD[i][j] = mfma16(af[i], bd[j], accD[i][j]);
    __syncthreads();
    cur ^= 1;
  }
  float* cp = Cpart + (long)z * B_ * KT;
  #pragma unroll
  for(int i = 0; i < 2; i++)
    #pragma unroll
    for(int j = 0; j < 4; j++){
      int doc = m0 + w * 32 + i * 16 + q * 4;
      int tg = t0 + j * 16 + lm;
      if(tg < KT){
        #pragma unroll
        for(int r = 0; r < 4; r++)
          cp[(long)(doc + r) * KT + tg] = accD[i][j][r];
      }
    }
}

// ---------------- per-doc backward (reduce colsum partials) + forward finalize ----------------
__global__ __launch_bounds__(64) void k_bwd(const float* __restrict__ colsum_part,
                                            const float* __restrict__ thn_f,
                                            const float* __restrict__ fwd_part,
                                            const float* __restrict__ ntok_acc,
                                            float* __restrict__ bwd_pd,
                                            float* __restrict__ fwd_pd){
  int b = blockIdx.x, lane = threadIdx.x;
  float s = 0.f;
  for(int t = lane; t < KT; t += 64){
    float cs = 0.f;
    #pragma unroll 8
    for(int z = 0; z < ZCS; z++) cs += colsum_part[((long)z * B_ + b) * KT + t];
    s += thn_f[(long)b * KT + t] * __builtin_amdgcn_rcpf(cs + 1e-30f);
  }
  float fp = 0.f;
  for(int p = lane; p < NVB; p += 64) fp += fwd_part[(long)b * NVB + p];
  #pragma unroll
  for(int k = 32; k >= 1; k >>= 1){ s += __shfl_xor(s, k, 64); fp += __shfl_xor(fp, k, 64); }
  if(lane == 0){
    float nt = ntok_acc[b];
    bwd_pd[b] = s * nt;                     // A[b,k] == ntok[b] (bows @ 1)
    fwd_pd[b] = fp / fmaxf(nt, 1.f);
  }
}

// ---------------- final reduce + 3 outputs ----------------
__global__ __launch_bounds__(512) void k_final(const float* __restrict__ bwd_pd,
                                               const float* __restrict__ fwd_pd,
                                               const float* __restrict__ ntok_acc,
                                               const float* __restrict__ tm_acc,
                                               float* __restrict__ out){
  __shared__ float rf[8], rb[8];
  int tid = threadIdx.x, w = tid >> 6, lane = tid & 63;
  bool valid = ntok_acc[tid] > 0.f;
  float fw = valid ? fwd_pd[tid] : 0.f;
  float bw = valid ? bwd_pd[tid] : 0.f;
  #pragma unroll
  for(int s = 32; s >= 1; s >>= 1){ fw += __shfl_xor(fw, s, 64); bw += __shfl_xor(bw, s, 64); }
  if(lane == 0){ rf[w] = fw; rb[w] = bw; }
  __syncthreads();
  if(tid == 0){
    float F = 0.f, Bw = 0.f;
    #pragma unroll
    for(int i = 0; i < 8; i++){ F += rf[i]; Bw += rb[i]; }
    out[0] = 1.0f * (-tm_acc[0] / (float)B_);  // EPSILON * tm
    out[1] = 0.5f * F;                         // BETA * forward
    out[2] = 0.5f * Bw;                        // (1-BETA) * backward
  }
}

extern "C" void kernel_launch(void* const* d_in, const int* in_sizes, int n_in,
                              void* d_out, int out_size, void* d_ws, size_t ws_size,
                              hipStream_t stream){
  const float* bows  = (const float*)d_in[0];
  const float* rho   = (const float*)d_in[1];
  const float* alpha = (const float*)d_in[2];
  const float* W1    = (const float*)d_in[3];
  const float* b1    = (const float*)d_in[4];
  const float* W2    = (const float*)d_in[5];
  const float* b2    = (const float*)d_in[6];
  float* out = (float*)d_out;
  char* ws = (char*)d_ws;
  size_t o = 0;
  auto alloc = [&](size_t bytes) -> char* {
    char* p = ws + o; o = (o + bytes + 255) & ~(size_t)255; return p;
  };
  // zeroed region (contiguous, zeroed every launch; small)
  float* sumexp     = (float*)alloc(KP * 4);
  float* ntok_acc   = (float*)alloc(B_ * 4);
  float* tm_acc     = (float*)alloc(256);
  float* bwd_pd     = (float*)alloc(B_ * 4);
  float* fwd_pd     = (float*)alloc(B_ * 4);
  size_t zbytes = o;
  // scratch (fully written before read)
  short* bows_b     = (short*)alloc((size_t)B_ * VP * 2);
  short* W1t        = (short*)alloc((size_t)HIDN * VP * 2);
  short* rho_p      = (short*)alloc((size_t)V_ * HP * 2);
  short* alpha_p    = (short*)alloc((size_t)KT * HP * 2);
  short* thetas_b   = (short*)alloc((size_t)B_ * KP * 2);
  short* thetan_b   = (short*)alloc((size_t)B_ * KP * 2);
  float* thetan_f   = (float*)alloc((size_t)B_ * KT * 4);
  short* dis_t      = (short*)alloc((size_t)KP * VP * 2);
  short* dis_v      = (short*)alloc((size_t)VP * KP * 2);
  float* fwd_part   = (float*)alloc((size_t)B_ * NVB * 4);
  float* hid_part   = (float*)alloc((size_t)ZG1 * B_ * HIDN * 4);   // 52.4 MB
  float* colsum_part= (float*)alloc((size_t)ZCS * B_ * KT * 4);     // 18.8 MB

  kzero<<<8, 256, 0, stream>>>((float*)ws, (long)(zbytes / 4));
  k_bows<<<dim3(25, 512), 256, 0, stream>>>(bows, bows_b, ntok_acc);
  k_transW1<<<dim3(VP / 32, HIDN / 32), 256, 0, stream>>>(W1, W1t);
  kconvpad<<<V_, HP, 0, stream>>>(rho, rho_p, HH, HP);
  kconvpad<<<KT, HP, 0, stream>>>(alpha, alpha_p, HH, HP);
  k_inner<<<dim3(VP / 128, 4), 256, 0, stream>>>(rho_p, alpha_p, dis_t, dis_v, sumexp);
  k_gemm1<<<dim3(896), 256, 0, stream>>>(bows_b, W1t, hid_part);
  k_theta<<<B_, 256, 0, stream>>>(hid_part, b1, W2, b2, sumexp, thetas_b, thetan_b, thetan_f);
  k_consumer<<<dim3(NVB, 4), 256, 0, stream>>>(dis_v, thetan_b, thetas_b, bows_b,
                                               fwd_part, tm_acc);
  k_colsum<<<dim3(736), 256, 0, stream>>>(bows_b, dis_t, colsum_part);
  k_bwd<<<B_, 64, 0, stream>>>(colsum_part, thetan_f, fwd_part, ntok_acc, bwd_pd, fwd_pd);
  k_final<<<1, 512, 0, stream>>>(bwd_pd, fwd_pd, ntok_acc, tm_acc, out);
}